// Round 1
// baseline (632.966 us; speedup 1.0000x reference)
//
#include <hip/hip_runtime.h>
#include <stdint.h>

typedef unsigned short u16;
typedef float f32x4 __attribute__((ext_vector_type(4)));
typedef short bf16x8 __attribute__((ext_vector_type(8)));

// ---------- helpers ----------
static __device__ __forceinline__ u16 f2bf(float f) {
  union { float f; unsigned u; } a; a.f = f;
  unsigned r = a.u + 0x7fffu + ((a.u >> 16) & 1u);   // round-nearest-even
  return (u16)(r >> 16);
}

static __device__ __forceinline__ void gload_lds16(const void* g, void* l) {
  __builtin_amdgcn_global_load_lds(
      (const __attribute__((address_space(1))) void*)(uintptr_t)g,
      (__attribute__((address_space(3))) void*)(uintptr_t)l,
      16, 0, 0);
}

// ---------- cast fp32 [rows][cols] -> bf16 [rows][ldd] ----------
__global__ __launch_bounds__(256) void cast_strided(
    const float* __restrict__ src, u16* __restrict__ dst,
    int rows, int cols, int ldd) {
  const size_t total = (size_t)rows * cols / 4;
  for (size_t i = (size_t)blockIdx.x * 256 + threadIdx.x; i < total;
       i += (size_t)gridDim.x * 256) {
    const size_t e = i * 4;
    const int r = (int)(e / cols);
    const int c = (int)(e % cols);
    float4 v = *(const float4*)(src + e);
    ushort4 o;
    o.x = f2bf(v.x); o.y = f2bf(v.y); o.z = f2bf(v.z); o.w = f2bf(v.w);
    *(ushort4*)(dst + (size_t)r * ldd + c) = o;
  }
}

// ---------- B [E=8][O=4096][R=16] * SCALING -> Waug[:, 4096:4224] bf16 ----------
__global__ __launch_bounds__(256) void cast_b2(
    const float* __restrict__ B, u16* __restrict__ Waug) {
  int i = blockIdx.x * 256 + threadIdx.x;
  if (i >= 4096 * 128) return;
  const int o = i >> 7;
  const int er = i & 127;
  const int e = er >> 4;
  const int r = er & 15;
  float v = B[((size_t)e * 4096 + o) * 16 + r] * 2.0f;   // SCALING = 32/16
  Waug[(size_t)o * 4224 + 4096 + er] = f2bf(v);
}

// ---------- gating: 1 wave per token ----------
__global__ __launch_bounds__(256) void gate_kernel(
    const float* __restrict__ x, const float* __restrict__ Wg,
    float* __restrict__ wsc) {
  const int lane = threadIdx.x & 63;
  const int wv = threadIdx.x >> 6;
  const int n = blockIdx.x * 4 + wv;
  const float4* x4 = (const float4*)(x + (size_t)n * 4096);
  const float4* g4 = (const float4*)Wg;                  // [8][1024] float4
  float acc[8] = {0, 0, 0, 0, 0, 0, 0, 0};
  for (int i = lane; i < 1024; i += 64) {
    float4 xv = x4[i];
#pragma unroll
    for (int e = 0; e < 8; ++e) {
      float4 w4 = g4[e * 1024 + i];
      acc[e] += xv.x * w4.x + xv.y * w4.y + xv.z * w4.z + xv.w * w4.w;
    }
  }
#pragma unroll
  for (int e = 0; e < 8; ++e) {
#pragma unroll
    for (int off = 32; off > 0; off >>= 1)
      acc[e] += __shfl_xor(acc[e], off);
  }
  // all lanes hold all 8 logits; top-2 with first-index tie-break
  int i1 = 0; float m1 = acc[0];
#pragma unroll
  for (int e = 1; e < 8; ++e) if (acc[e] > m1) { m1 = acc[e]; i1 = e; }
  int i2 = -1; float m2 = -3.4e38f;
#pragma unroll
  for (int e = 0; e < 8; ++e) if (e != i1 && acc[e] > m2) { m2 = acc[e]; i2 = e; }
  float w1 = 1.0f / (1.0f + expf(m2 - m1));  // p1/(p1+p2) after softmax+renorm
  float w2 = 1.0f - w1;
  if (lane < 8)
    wsc[(size_t)n * 8 + lane] = (lane == i1) ? w1 : ((lane == i2) ? w2 : 0.0f);
}

// ---------- hw = h * w -> Xaug[:, 4096:4224] bf16 ----------
__global__ __launch_bounds__(256) void hw_kernel(
    const float* __restrict__ h, const float* __restrict__ wsc,
    u16* __restrict__ Xaug) {
  int i = blockIdx.x * 256 + threadIdx.x;
  if (i >= 8192 * 128) return;
  const int n = i >> 7;
  const int er = i & 127;
  const int e = er >> 4;
  float v = h[i] * wsc[n * 8 + e];
  Xaug[(size_t)n * 4224 + 4096 + er] = f2bf(v);
}

// ---------- bf16 GEMM, C[n,o] = sum_k A[n,k]*B[o,k] (+bias), m97 structure ----------
// 128x128 tile, BK=64, 4 waves (2x2), each wave 64x64 (4x4 frags of 16x16x32)
template <bool BIAS>
__global__ __launch_bounds__(256) void gemm_bt(
    const u16* __restrict__ Ag, const u16* __restrict__ Bg,
    const float* __restrict__ bias, float* __restrict__ C,
    int lda, int ldb, int ldc, int K) {
  __shared__ u16 sA[128 * 64];
  __shared__ u16 sB[128 * 64];
  const int t = threadIdx.x;
  const int lane = t & 63;
  const int wr = t >> 7;            // wave row (0..1)
  const int wc = (t >> 6) & 1;      // wave col (0..1)
  const int l15 = lane & 15;
  const int lhi = lane >> 4;        // 0..3
  f32x4 acc[4][4] = {};

  const int brow = blockIdx.x * 128;
  const int bcol = blockIdx.y * 128;
  const int srow = t >> 3;          // staging row within 32-row group
  const int scol = (t & 7) * 8;     // staging col (elements)
  const size_t a_src = (size_t)(brow + srow) * lda + scol;
  const size_t b_src = (size_t)(bcol + srow) * ldb + scol;

  for (int k0 = 0; k0 < K; k0 += 64) {
#pragma unroll
    for (int c = 0; c < 4; ++c)
      gload_lds16(Ag + a_src + (size_t)c * 32 * lda + k0,
                  &sA[(c * 32 + srow) * 64 + scol]);
#pragma unroll
    for (int c = 0; c < 4; ++c)
      gload_lds16(Bg + b_src + (size_t)c * 32 * ldb + k0,
                  &sB[(c * 32 + srow) * 64 + scol]);
    __syncthreads();
#pragma unroll
    for (int kk = 0; kk < 2; ++kk) {
      bf16x8 av[4], bv[4];
#pragma unroll
      for (int m = 0; m < 4; ++m)
        av[m] = *(const bf16x8*)&sA[(wr * 64 + m * 16 + l15) * 64 + kk * 32 + lhi * 8];
#pragma unroll
      for (int n = 0; n < 4; ++n)
        bv[n] = *(const bf16x8*)&sB[(wc * 64 + n * 16 + l15) * 64 + kk * 32 + lhi * 8];
#pragma unroll
      for (int m = 0; m < 4; ++m)
#pragma unroll
        for (int n = 0; n < 4; ++n)
          acc[m][n] = __builtin_amdgcn_mfma_f32_16x16x32_bf16(av[m], bv[n], acc[m][n], 0, 0, 0);
    }
    __syncthreads();
  }
  // epilogue: C/D layout col = lane&15, row = (lane>>4)*4 + j   [m89/m91]
#pragma unroll
  for (int m = 0; m < 4; ++m) {
    const int rbase = brow + wr * 64 + m * 16 + lhi * 4;
#pragma unroll
    for (int n = 0; n < 4; ++n) {
      const int col = bcol + wc * 64 + n * 16 + l15;
      const float bv2 = BIAS ? bias[col] : 0.0f;
#pragma unroll
      for (int j = 0; j < 4; ++j)
        C[(size_t)(rbase + j) * ldc + col] = acc[m][n][j] + bv2;
    }
  }
}

// ---------- launch ----------
extern "C" void kernel_launch(void* const* d_in, const int* in_sizes, int n_in,
                              void* d_out, int out_size, void* d_ws, size_t ws_size,
                              hipStream_t stream) {
  const float* x  = (const float*)d_in[0];   // [8192][4096]
  const float* Wb = (const float*)d_in[1];   // [4096][4096]
  const float* bb = (const float*)d_in[2];   // [4096]
  const float* Wg = (const float*)d_in[3];   // [8][4096]
  const float* A  = (const float*)d_in[4];   // [8][16][4096] = [128][4096]
  const float* B  = (const float*)d_in[5];   // [8][4096][16]
  float* out = (float*)d_out;                // [8192][4096]

  char* ws = (char*)d_ws;
  u16*   Xaug = (u16*)ws;                                   // 8192 x 4224 bf16
  u16*   Waug = (u16*)(ws + 69206016);                      // 4096 x 4224 bf16
  u16*   a2   = (u16*)(ws + 69206016 + 34603008);           // 128 x 4096 bf16
  float* h    = (float*)(ws + 69206016 + 34603008 + 1048576);         // 8192 x 128
  float* wsc  = (float*)(ws + 69206016 + 34603008 + 1048576 + 4194304); // 8192 x 8

  // 1) casts into augmented operand buffers
  cast_strided<<<4096, 256, 0, stream>>>(x,  Xaug, 8192, 4096, 4224);
  cast_strided<<<2048, 256, 0, stream>>>(Wb, Waug, 4096, 4096, 4224);
  cast_strided<<<512,  256, 0, stream>>>(A,  a2,   128,  4096, 4096);
  cast_b2<<<2048, 256, 0, stream>>>(B, Waug);

  // 2) gating weights (fp32, exact path)
  gate_kernel<<<2048, 256, 0, stream>>>(x, Wg, wsc);

  // 3) LoRA down-proj: h[8192][128] = x @ A^T
  gemm_bt<false><<<dim3(64, 1), 256, 0, stream>>>(Xaug, a2, nullptr, h,
                                                  4224, 4096, 128, 4096);

  // 4) hw = h * gate_w -> Xaug[:, 4096:]
  hw_kernel<<<4096, 256, 0, stream>>>(h, wsc, Xaug);

  // 5) main fused GEMM: out = Xaug @ Waug^T + bias  (base + moe in one K=4224 pass)
  gemm_bt<true><<<dim3(64, 32), 256, 0, stream>>>(Xaug, Waug, bb, out,
                                                  4224, 4224, 4096, 4224);
}

// Round 2
// 489.307 us; speedup vs baseline: 1.2936x; 1.2936x over previous
//
#include <hip/hip_runtime.h>
#include <stdint.h>

typedef unsigned short u16;
typedef float f32x4 __attribute__((ext_vector_type(4)));
typedef short bf16x8 __attribute__((ext_vector_type(8)));
typedef uint32_t u32x4 __attribute__((ext_vector_type(4)));

// ---------- helpers ----------
static __device__ __forceinline__ u16 f2bf(float f) {
  union { float f; unsigned u; } a; a.f = f;
  unsigned r = a.u + 0x7fffu + ((a.u >> 16) & 1u);   // round-nearest-even
  return (u16)(r >> 16);
}

static __device__ __forceinline__ void gload_lds16(const void* g, void* l) {
  __builtin_amdgcn_global_load_lds(
      (const __attribute__((address_space(1))) void*)(uintptr_t)g,
      (__attribute__((address_space(3))) void*)(uintptr_t)l,
      16, 0, 0);
}

// ---------- cast fp32 [rows][cols] -> bf16 [rows][ldd] ----------
__global__ __launch_bounds__(256) void cast_strided(
    const float* __restrict__ src, u16* __restrict__ dst,
    int rows, int cols, int ldd) {
  const size_t total = (size_t)rows * cols / 4;
  for (size_t i = (size_t)blockIdx.x * 256 + threadIdx.x; i < total;
       i += (size_t)gridDim.x * 256) {
    const size_t e = i * 4;
    const int r = (int)(e / cols);
    const int c = (int)(e % cols);
    float4 v = *(const float4*)(src + e);
    ushort4 o;
    o.x = f2bf(v.x); o.y = f2bf(v.y); o.z = f2bf(v.z); o.w = f2bf(v.w);
    *(ushort4*)(dst + (size_t)r * ldd + c) = o;
  }
}

// ---------- B [E=8][O=4096][R=16] * SCALING -> Waug[:, 4096:4224] bf16 ----------
__global__ __launch_bounds__(256) void cast_b2(
    const float* __restrict__ B, u16* __restrict__ Waug) {
  int i = blockIdx.x * 256 + threadIdx.x;
  if (i >= 4096 * 128) return;
  const int o = i >> 7;
  const int er = i & 127;
  const int e = er >> 4;
  const int r = er & 15;
  float v = B[((size_t)e * 4096 + o) * 16 + r] * 2.0f;   // SCALING = 32/16
  Waug[(size_t)o * 4224 + 4096 + er] = f2bf(v);
}

// ---------- gating: 1 wave per token ----------
__global__ __launch_bounds__(256) void gate_kernel(
    const float* __restrict__ x, const float* __restrict__ Wg,
    float* __restrict__ wsc) {
  const int lane = threadIdx.x & 63;
  const int wv = threadIdx.x >> 6;
  const int n = blockIdx.x * 4 + wv;
  const float4* x4 = (const float4*)(x + (size_t)n * 4096);
  const float4* g4 = (const float4*)Wg;                  // [8][1024] float4
  float acc[8] = {0, 0, 0, 0, 0, 0, 0, 0};
  for (int i = lane; i < 1024; i += 64) {
    float4 xv = x4[i];
#pragma unroll
    for (int e = 0; e < 8; ++e) {
      float4 w4 = g4[e * 1024 + i];
      acc[e] += xv.x * w4.x + xv.y * w4.y + xv.z * w4.z + xv.w * w4.w;
    }
  }
#pragma unroll
  for (int e = 0; e < 8; ++e) {
#pragma unroll
    for (int off = 32; off > 0; off >>= 1)
      acc[e] += __shfl_xor(acc[e], off);
  }
  int i1 = 0; float m1 = acc[0];
#pragma unroll
  for (int e = 1; e < 8; ++e) if (acc[e] > m1) { m1 = acc[e]; i1 = e; }
  int i2 = -1; float m2 = -3.4e38f;
#pragma unroll
  for (int e = 0; e < 8; ++e) if (e != i1 && acc[e] > m2) { m2 = acc[e]; i2 = e; }
  float w1 = 1.0f / (1.0f + expf(m2 - m1));
  float w2 = 1.0f - w1;
  if (lane < 8)
    wsc[(size_t)n * 8 + lane] = (lane == i1) ? w1 : ((lane == i2) ? w2 : 0.0f);
}

// ---------- hw = h * w -> Xaug[:, 4096:4224] bf16 ----------
__global__ __launch_bounds__(256) void hw_kernel(
    const float* __restrict__ h, const float* __restrict__ wsc,
    u16* __restrict__ Xaug) {
  int i = blockIdx.x * 256 + threadIdx.x;
  if (i >= 8192 * 128) return;
  const int n = i >> 7;
  const int er = i & 127;
  const int e = er >> 4;
  float v = h[i] * wsc[n * 8 + e];
  Xaug[(size_t)n * 4224 + 4096 + er] = f2bf(v);
}

// ---------- small bf16 GEMM (m97 structure) for the LoRA down-proj ----------
template <bool BIAS>
__global__ __launch_bounds__(256) void gemm_bt(
    const u16* __restrict__ Ag, const u16* __restrict__ Bg,
    const float* __restrict__ bias, float* __restrict__ C,
    int lda, int ldb, int ldc, int K) {
  __shared__ u16 sA[128 * 64];
  __shared__ u16 sB[128 * 64];
  const int t = threadIdx.x;
  const int lane = t & 63;
  const int wr = t >> 7;
  const int wc = (t >> 6) & 1;
  const int l15 = lane & 15;
  const int lhi = lane >> 4;
  f32x4 acc[4][4] = {};

  const int brow = blockIdx.x * 128;
  const int bcol = blockIdx.y * 128;
  const int srow = t >> 3;
  const int scol = (t & 7) * 8;
  const size_t a_src = (size_t)(brow + srow) * lda + scol;
  const size_t b_src = (size_t)(bcol + srow) * ldb + scol;

  for (int k0 = 0; k0 < K; k0 += 64) {
#pragma unroll
    for (int c = 0; c < 4; ++c)
      gload_lds16(Ag + a_src + (size_t)c * 32 * lda + k0,
                  &sA[(c * 32 + srow) * 64 + scol]);
#pragma unroll
    for (int c = 0; c < 4; ++c)
      gload_lds16(Bg + b_src + (size_t)c * 32 * ldb + k0,
                  &sB[(c * 32 + srow) * 64 + scol]);
    __syncthreads();
#pragma unroll
    for (int kk = 0; kk < 2; ++kk) {
      bf16x8 av[4], bv[4];
#pragma unroll
      for (int m = 0; m < 4; ++m)
        av[m] = *(const bf16x8*)&sA[(wr * 64 + m * 16 + l15) * 64 + kk * 32 + lhi * 8];
#pragma unroll
      for (int n = 0; n < 4; ++n)
        bv[n] = *(const bf16x8*)&sB[(wc * 64 + n * 16 + l15) * 64 + kk * 32 + lhi * 8];
#pragma unroll
      for (int m = 0; m < 4; ++m)
#pragma unroll
        for (int n = 0; n < 4; ++n)
          acc[m][n] = __builtin_amdgcn_mfma_f32_16x16x32_bf16(av[m], bv[n], acc[m][n], 0, 0, 0);
    }
    __syncthreads();
  }
#pragma unroll
  for (int m = 0; m < 4; ++m) {
    const int rbase = brow + wr * 64 + m * 16 + lhi * 4;
#pragma unroll
    for (int n = 0; n < 4; ++n) {
      const int col = bcol + wc * 64 + n * 16 + l15;
      const float bv2 = BIAS ? bias[col] : 0.0f;
#pragma unroll
      for (int j = 0; j < 4; ++j)
        C[(size_t)(rbase + j) * ldc + col] = acc[m][n][j] + bv2;
    }
  }
}

// ================== 256x256 8-phase main GEMM (reg-staged, swizzled LDS) ==================
// C[n,o] = sum_k A[n,k]*B[o,k] + bias[o].  BM=BN=256, BK=64, 512 thr (8 waves 2x4),
// per-wave 128x64 out (8x4 frags of 16x16x32).  LDS: 2 bufs x (A 32KB + B 32KB),
// 16x32-elem subtiles (1024B) with XOR-bit5 swizzle (T2).  Reg-staged pipeline:
// chunks for kt+2/kt+3 load 4 phases before their ds_write (T14); publishing
// barriers use lgkmcnt(0) only (no vmcnt drain -> loads stay in flight, T4).
#define BAR do { asm volatile("" ::: "memory"); __builtin_amdgcn_s_barrier(); asm volatile("" ::: "memory"); } while (0)
#define BARPUB do { asm volatile("s_waitcnt lgkmcnt(0)" ::: "memory"); __builtin_amdgcn_s_barrier(); asm volatile("" ::: "memory"); } while (0)

#define LDC(ARR, C, KO)                                                         \
  ARR[C] = *(const u32x4*)(((C) >= 4 ? bptr + (size_t)(((C) & 3) * 64) * ldb    \
                                     : aptr + (size_t)(((C) & 3) * 64) * lda) + (KO));

#define WRC(ARR, C, BUF)                                                        \
  *(u32x4*)(lds + (BUF) + ((C) >= 4 ? 32768 : 0) + (((C) & 3) << 13) + stbase) = ARR[C];

#define RDA(BUF, MH)                                                            \
  { _Pragma("unroll") for (int mm = 0; mm < 4; ++mm)                            \
    _Pragma("unroll") for (int kk = 0; kk < 2; ++kk)                            \
      av[mm][kk] = *(const bf16x8*)(lds + (BUF) + fbA + ((((MH) * 4 + mm) * 2 + kk) << 10)); }

#define RDB(BUF, NH)                                                            \
  { _Pragma("unroll") for (int nn = 0; nn < 2; ++nn)                            \
    _Pragma("unroll") for (int kk = 0; kk < 2; ++kk)                            \
      bv[nn][kk] = *(const bf16x8*)(lds + (BUF) + fbB + ((((NH) * 2 + nn) * 2 + kk) << 10)); }

#define MFMAQ(MH, NH)                                                           \
  { __builtin_amdgcn_s_setprio(1);                                              \
    _Pragma("unroll") for (int kk = 0; kk < 2; ++kk)                            \
    _Pragma("unroll") for (int mm = 0; mm < 4; ++mm)                            \
    _Pragma("unroll") for (int nn = 0; nn < 2; ++nn)                            \
      acc[(MH) * 4 + mm][(NH) * 2 + nn] = __builtin_amdgcn_mfma_f32_16x16x32_bf16( \
          av[mm][kk], bv[nn][kk], acc[(MH) * 4 + mm][(NH) * 2 + nn], 0, 0, 0);  \
    __builtin_amdgcn_s_setprio(0); }

__global__ __launch_bounds__(512, 2) void gemm8p(
    const u16* __restrict__ Ag, const u16* __restrict__ Bg,
    const float* __restrict__ bias, float* __restrict__ C,
    int lda, int ldb, int ldc, int K, int tiles_n) {
  __shared__ char lds[131072];
  const int t = threadIdx.x;
  const int lane = t & 63;
  const int w = t >> 6;
  const int wr = w >> 2, wc = w & 3;
  const int l15 = lane & 15, lhi = lane >> 4;

  // bijective XCD swizzle (gridDim.x % 8 == 0)
  const int cpx = gridDim.x >> 3;
  const int bid = blockIdx.x;
  const int swz = (bid & 7) * cpx + (bid >> 3);
  const int tile_m = swz / tiles_n;
  const int tile_n = swz % tiles_n;
  const int brow = tile_m << 8;
  const int bcol = tile_n << 8;

  // staging coords: thread t covers row=j*64+(t>>3), col=(t&7)*8 per chunk j
  const int arow = t >> 3;
  const int acol = (t & 7) << 3;
  const u16* aptr = Ag + (size_t)(brow + arow) * lda + acol;
  const u16* bptr = Bg + (size_t)(bcol + arow) * ldb + acol;
  const int stbase = ((arow >> 4) << 11) + ((acol >> 5) << 10) +
                     ((((arow & 15) << 6) + ((acol & 31) << 1)) ^ (((arow >> 3) & 1) << 5));
  // frag read bases (swizzled)
  const int innerL = ((l15 << 6) + (lhi << 4)) ^ (((l15 >> 3) & 1) << 5);
  const int fbA = (wr << 14) + innerL;
  const int fbB = 32768 + (wc << 13) + innerL;

  f32x4 acc[8][4] = {};
  bf16x8 av[4][2], bv[2][2];
  u32x4 P[8], Q[8];

  const int NT = K >> 6;        // 66 K-tiles
  const int NIT = NT >> 1;      // 33 iterations (2 K-tiles each)

  // ---- prologue: kt0 -> Q -> buf0 ; kt1 -> P (written during first group A) ----
#pragma unroll
  for (int c = 0; c < 8; ++c) { LDC(Q, c, 0) }
#pragma unroll
  for (int c = 0; c < 8; ++c) { LDC(P, c, 64) }
#pragma unroll
  for (int c = 0; c < 8; ++c) { WRC(Q, c, 0) }
  BARPUB;

  for (int it = 0; it < NIT; ++it) {
    const int kt2 = 2 * it + 2, kt3 = 2 * it + 3;
    const int kA = (kt2 < NT ? kt2 : NT - 1) << 6;
    const int kB = (kt3 < NT ? kt3 : NT - 1) << 6;
    // ======== GROUP A: compute buf0 (kt); write P(kt+1)->buf1; load Q<-kt+2 ========
    // ph0
    RDA(0, 0); RDB(0, 0);
    LDC(Q, 0, kA) LDC(Q, 1, kA)
    WRC(P, 0, 65536) WRC(P, 1, 65536)
    BAR; MFMAQ(0, 0); BAR;
    // ph1
    RDB(0, 1);
    LDC(Q, 2, kA) LDC(Q, 3, kA)
    WRC(P, 2, 65536) WRC(P, 3, 65536)
    BAR; MFMAQ(0, 1); BAR;
    // ph2
    RDA(0, 1);
    LDC(Q, 4, kA) LDC(Q, 5, kA)
    WRC(P, 4, 65536) WRC(P, 5, 65536)
    BAR; MFMAQ(1, 1); BAR;
    // ph3
    RDB(0, 0);
    LDC(Q, 6, kA) LDC(Q, 7, kA)
    WRC(P, 6, 65536) WRC(P, 7, 65536)
    BAR; MFMAQ(1, 0); BARPUB;          // publish buf1 (kt+1)
    // ======== GROUP B: compute buf1 (kt+1); write Q(kt+2)->buf0; load P<-kt+3 ========
    // ph4
    RDA(65536, 0); RDB(65536, 0);
    LDC(P, 0, kB) LDC(P, 1, kB)
    WRC(Q, 0, 0) WRC(Q, 1, 0)
    BAR; MFMAQ(0, 0); BAR;
    // ph5
    RDB(65536, 1);
    LDC(P, 2, kB) LDC(P, 3, kB)
    WRC(Q, 2, 0) WRC(Q, 3, 0)
    BAR; MFMAQ(0, 1); BAR;
    // ph6
    RDA(65536, 1);
    LDC(P, 4, kB) LDC(P, 5, kB)
    WRC(Q, 4, 0) WRC(Q, 5, 0)
    BAR; MFMAQ(1, 1); BAR;
    // ph7
    RDB(65536, 0);
    LDC(P, 6, kB) LDC(P, 7, kB)
    WRC(Q, 6, 0) WRC(Q, 7, 0)
    BAR; MFMAQ(1, 0); BARPUB;          // publish buf0 (kt+2)
  }

  // ---- epilogue: C = acc + bias ----
#pragma unroll
  for (int m = 0; m < 8; ++m) {
    const int row0 = brow + wr * 128 + m * 16 + lhi * 4;
#pragma unroll
    for (int n = 0; n < 4; ++n) {
      const int col = bcol + wc * 64 + n * 16 + l15;
      const float b2 = bias[col];
#pragma unroll
      for (int j = 0; j < 4; ++j)
        C[(size_t)(row0 + j) * ldc + col] = acc[m][n][j] + b2;
    }
  }
}

// ---------- launch ----------
extern "C" void kernel_launch(void* const* d_in, const int* in_sizes, int n_in,
                              void* d_out, int out_size, void* d_ws, size_t ws_size,
                              hipStream_t stream) {
  const float* x  = (const float*)d_in[0];   // [8192][4096]
  const float* Wb = (const float*)d_in[1];   // [4096][4096]
  const float* bb = (const float*)d_in[2];   // [4096]
  const float* Wg = (const float*)d_in[3];   // [8][4096]
  const float* A  = (const float*)d_in[4];   // [8][16][4096] = [128][4096]
  const float* B  = (const float*)d_in[5];   // [8][4096][16]
  float* out = (float*)d_out;                // [8192][4096]

  char* ws = (char*)d_ws;
  u16*   Xaug = (u16*)ws;                                   // 8192 x 4224 bf16
  u16*   Waug = (u16*)(ws + 69206016);                      // 4096 x 4224 bf16
  u16*   a2   = (u16*)(ws + 69206016 + 34603008);           // 128 x 4096 bf16
  float* h    = (float*)(ws + 69206016 + 34603008 + 1048576);            // 8192 x 128
  float* wsc  = (float*)(ws + 69206016 + 34603008 + 1048576 + 4194304);  // 8192 x 8

  // 1) casts into augmented operand buffers
  cast_strided<<<4096, 256, 0, stream>>>(x,  Xaug, 8192, 4096, 4224);
  cast_strided<<<2048, 256, 0, stream>>>(Wb, Waug, 4096, 4096, 4224);
  cast_strided<<<512,  256, 0, stream>>>(A,  a2,   128,  4096, 4096);
  cast_b2<<<2048, 256, 0, stream>>>(B, Waug);

  // 2) gating weights (fp32, exact path)
  gate_kernel<<<2048, 256, 0, stream>>>(x, Wg, wsc);

  // 3) LoRA down-proj: h[8192][128] = x @ A^T
  gemm_bt<false><<<dim3(64, 1), 256, 0, stream>>>(Xaug, a2, nullptr, h,
                                                  4224, 4096, 128, 4096);

  // 4) hw = h * gate_w -> Xaug[:, 4096:]
  hw_kernel<<<4096, 256, 0, stream>>>(h, wsc, Xaug);

  // 5) main fused GEMM: out = Xaug @ Waug^T + bias (256^2 8-phase)
  gemm8p<<<512, 512, 0, stream>>>(Xaug, Waug, bb, out, 4224, 4224, 4096, 4224, 16);
}

// Round 3
// 440.260 us; speedup vs baseline: 1.4377x; 1.1114x over previous
//
#include <hip/hip_runtime.h>
#include <stdint.h>

typedef unsigned short u16;
typedef float f32x4 __attribute__((ext_vector_type(4)));
typedef short bf16x8 __attribute__((ext_vector_type(8)));

// ---------- helpers ----------
static __device__ __forceinline__ u16 f2bf(float f) {
  union { float f; unsigned u; } a; a.f = f;
  unsigned r = a.u + 0x7fffu + ((a.u >> 16) & 1u);   // round-nearest-even
  return (u16)(r >> 16);
}

static __device__ __forceinline__ void gld16(const void* g, void* l) {
  __builtin_amdgcn_global_load_lds(
      (const __attribute__((address_space(1))) void*)(uintptr_t)g,
      (__attribute__((address_space(3))) void*)(uintptr_t)l,
      16, 0, 0);
}

// ---------- cast fp32 [rows][cols] -> bf16 [rows][ldd] ----------
__global__ __launch_bounds__(256) void cast_strided(
    const float* __restrict__ src, u16* __restrict__ dst,
    int rows, int cols, int ldd) {
  const size_t total = (size_t)rows * cols / 4;
  for (size_t i = (size_t)blockIdx.x * 256 + threadIdx.x; i < total;
       i += (size_t)gridDim.x * 256) {
    const size_t e = i * 4;
    const int r = (int)(e / cols);
    const int c = (int)(e % cols);
    float4 v = *(const float4*)(src + e);
    ushort4 o;
    o.x = f2bf(v.x); o.y = f2bf(v.y); o.z = f2bf(v.z); o.w = f2bf(v.w);
    *(ushort4*)(dst + (size_t)r * ldd + c) = o;
  }
}

// ---------- B [E=8][O=4096][R=16] * SCALING -> Waug[:, 4096:4224] bf16 ----------
__global__ __launch_bounds__(256) void cast_b2(
    const float* __restrict__ B, u16* __restrict__ Waug) {
  int i = blockIdx.x * 256 + threadIdx.x;
  if (i >= 4096 * 128) return;
  const int o = i >> 7;
  const int er = i & 127;
  const int e = er >> 4;
  const int r = er & 15;
  float v = B[((size_t)e * 4096 + o) * 16 + r] * 2.0f;   // SCALING = 32/16
  Waug[(size_t)o * 4224 + 4096 + er] = f2bf(v);
}

// ---------- gating: 1 wave per token ----------
__global__ __launch_bounds__(256) void gate_kernel(
    const float* __restrict__ x, const float* __restrict__ Wg,
    float* __restrict__ wsc) {
  const int lane = threadIdx.x & 63;
  const int wv = threadIdx.x >> 6;
  const int n = blockIdx.x * 4 + wv;
  const float4* x4 = (const float4*)(x + (size_t)n * 4096);
  const float4* g4 = (const float4*)Wg;                  // [8][1024] float4
  float acc[8] = {0, 0, 0, 0, 0, 0, 0, 0};
  for (int i = lane; i < 1024; i += 64) {
    float4 xv = x4[i];
#pragma unroll
    for (int e = 0; e < 8; ++e) {
      float4 w4 = g4[e * 1024 + i];
      acc[e] += xv.x * w4.x + xv.y * w4.y + xv.z * w4.z + xv.w * w4.w;
    }
  }
#pragma unroll
  for (int e = 0; e < 8; ++e) {
#pragma unroll
    for (int off = 32; off > 0; off >>= 1)
      acc[e] += __shfl_xor(acc[e], off);
  }
  int i1 = 0; float m1 = acc[0];
#pragma unroll
  for (int e = 1; e < 8; ++e) if (acc[e] > m1) { m1 = acc[e]; i1 = e; }
  int i2 = -1; float m2 = -3.4e38f;
#pragma unroll
  for (int e = 0; e < 8; ++e) if (e != i1 && acc[e] > m2) { m2 = acc[e]; i2 = e; }
  float w1 = 1.0f / (1.0f + expf(m2 - m1));
  float w2 = 1.0f - w1;
  if (lane < 8)
    wsc[(size_t)n * 8 + lane] = (lane == i1) ? w1 : ((lane == i2) ? w2 : 0.0f);
}

// ---------- LoRA down-proj + fused gate-scale epilogue ----------
// h[n][er] = sum_k Xaug[n][k] * a2[er][k];  Xaug[n][4096+er] = bf16(h * wsc[n][er>>4])
__global__ __launch_bounds__(256) void lora_down(
    const u16* __restrict__ Xa, const u16* __restrict__ A2,
    const float* __restrict__ wsc, u16* __restrict__ Xaug) {
  __shared__ u16 sA[128 * 64];
  __shared__ u16 sB[128 * 64];
  const int t = threadIdx.x;
  const int lane = t & 63;
  const int wr = t >> 7;
  const int wc = (t >> 6) & 1;
  const int l15 = lane & 15;
  const int lhi = lane >> 4;
  f32x4 acc[4][4] = {};

  const int brow = blockIdx.x * 128;
  const int srow = t >> 3;
  const int scol = (t & 7) * 8;
  const size_t a_src = (size_t)(brow + srow) * 4224 + scol;
  const size_t b_src = (size_t)srow * 4096 + scol;

  for (int k0 = 0; k0 < 4096; k0 += 64) {
#pragma unroll
    for (int c = 0; c < 4; ++c)
      gld16(Xa + a_src + (size_t)c * 32 * 4224 + k0,
            &sA[(c * 32 + srow) * 64 + scol]);
#pragma unroll
    for (int c = 0; c < 4; ++c)
      gld16(A2 + b_src + (size_t)c * 32 * 4096 + k0,
            &sB[(c * 32 + srow) * 64 + scol]);
    __syncthreads();
#pragma unroll
    for (int kk = 0; kk < 2; ++kk) {
      bf16x8 av[4], bv[4];
#pragma unroll
      for (int m = 0; m < 4; ++m)
        av[m] = *(const bf16x8*)&sA[(wr * 64 + m * 16 + l15) * 64 + kk * 32 + lhi * 8];
#pragma unroll
      for (int n = 0; n < 4; ++n)
        bv[n] = *(const bf16x8*)&sB[(wc * 64 + n * 16 + l15) * 64 + kk * 32 + lhi * 8];
#pragma unroll
      for (int m = 0; m < 4; ++m)
#pragma unroll
        for (int n = 0; n < 4; ++n)
          acc[m][n] = __builtin_amdgcn_mfma_f32_16x16x32_bf16(av[m], bv[n], acc[m][n], 0, 0, 0);
    }
    __syncthreads();
  }
#pragma unroll
  for (int m = 0; m < 4; ++m) {
    const int rbase = brow + wr * 64 + m * 16 + lhi * 4;
#pragma unroll
    for (int n = 0; n < 4; ++n) {
      const int col = wc * 64 + n * 16 + l15;   // 0..127
#pragma unroll
      for (int j = 0; j < 4; ++j) {
        const int row = rbase + j;
        const float g = wsc[(size_t)row * 8 + (col >> 4)];
        Xaug[(size_t)row * 4224 + 4096 + col] = f2bf(acc[m][n][j] * g);
      }
    }
  }
}

// ================== 256x256 8-phase main GEMM (global_load_lds, pre-swizzled src) ==================
// C[n,o] = sum_k A[n,k]*B[o,k] + bias[o].  BM=BN=256, BK=64, 512 thr (8 waves 2x4),
// per-wave 128x64 out.  LDS: 2 bufs x (A 32KB + B 32KB), 16x32 subtiles with st_16x32
// XOR-bit5 swizzle achieved by pre-swizzling the per-lane GLOBAL source (m173/m201);
// LDS dest stays linear (lane*16).  Counted vmcnt(4) at each K-tile start (never 0 in
// the main loop); staging lands only in regions whose reads are fully drained
// (lgkmcnt(0)+barrier per phase).
#define BAR do { asm volatile("" ::: "memory"); __builtin_amdgcn_s_barrier(); asm volatile("" ::: "memory"); } while (0)
#define LGKM0 asm volatile("s_waitcnt lgkmcnt(0)" ::: "memory")

#define RDA(BUF, MH)                                                            \
  { _Pragma("unroll") for (int mm = 0; mm < 4; ++mm)                            \
    _Pragma("unroll") for (int kk = 0; kk < 2; ++kk)                            \
      av[mm][kk] = *(const bf16x8*)(lds + (BUF) + fbA + ((((MH) * 4 + mm) * 2 + kk) << 10)); }

#define RDB(BUF, NH)                                                            \
  { _Pragma("unroll") for (int nn = 0; nn < 2; ++nn)                            \
    _Pragma("unroll") for (int kk = 0; kk < 2; ++kk)                            \
      bv[(NH) * 2 + nn][kk] = *(const bf16x8*)(lds + (BUF) + fbB + ((((NH) * 2 + nn) * 2 + kk) << 10)); }

#define MFMAQ(MH, NH)                                                           \
  { __builtin_amdgcn_s_setprio(1);                                              \
    _Pragma("unroll") for (int kk = 0; kk < 2; ++kk)                            \
    _Pragma("unroll") for (int mm = 0; mm < 4; ++mm)                            \
    _Pragma("unroll") for (int nn = 0; nn < 2; ++nn)                            \
      acc[(MH) * 4 + mm][(NH) * 2 + nn] = __builtin_amdgcn_mfma_f32_16x16x32_bf16( \
          av[mm][kk], bv[(NH) * 2 + nn][kk], acc[(MH) * 4 + mm][(NH) * 2 + nn], 0, 0, 0); \
    __builtin_amdgcn_s_setprio(0); }

__global__ __launch_bounds__(512, 2) void gemm8p(
    const u16* __restrict__ Ag, const u16* __restrict__ Bg,
    const float* __restrict__ bias, float* __restrict__ C,
    int lda, int ldb, int ldc, int K, int tiles_n) {
  __shared__ __align__(1024) char lds[131072];
  const int t = threadIdx.x;
  const int lane = t & 63;
  const int w = t >> 6;
  const int wr = w >> 2, wc = w & 3;
  const int l15 = lane & 15, lhi = lane >> 4;

  // bijective XCD swizzle (gridDim.x % 8 == 0)
  const int cpx = gridDim.x >> 3;
  const int bid = blockIdx.x;
  const int swz = (bid & 7) * cpx + (bid >> 3);
  const int tile_m = swz / tiles_n;
  const int tile_n = swz % tiles_n;
  const int brow = tile_m << 8;
  const int bcol = tile_n << 8;

  // pre-swizzled per-lane source coords (st_16x32 involution):
  // lane L fills LDS bytes [L*16, L*16+16) of a 1024B subtile; content must be
  // logical bytes (L*16)^( (L&32) ) -> row sb>>6, col (sb&63)/2 of the 16x32 subtile.
  const int sb = (lane << 4) ^ (lane & 32);
  const int srow = sb >> 6;
  const int scol = (sb & 63) >> 1;

  // wave w stages A subtiles w*4..w*4+3 and B subtiles w*4..w*4+3 per K-tile
  const u16* pA[4]; const u16* pB[4];
#pragma unroll
  for (int s = 0; s < 4; ++s) {
    const int idx = w * 4 + s;
    const int rg = idx >> 1, cs = idx & 1;
    pA[s] = Ag + (size_t)(brow + rg * 16 + srow) * lda + cs * 32 + scol;
    pB[s] = Bg + (size_t)(bcol + rg * 16 + srow) * ldb + cs * 32 + scol;
  }
  const int ldsA = w << 12;            // w*4 subtiles * 1024B
  const int ldsB = 32768 + (w << 12);

  // fragment read bases (swizzled read of linear-written LDS)
  const int innerL = ((l15 << 6) + (lhi << 4)) ^ ((l15 & 8) << 2);
  const int fbA = (wr << 14) + innerL;
  const int fbB = 32768 + (wc << 13) + innerL;

  f32x4 acc[8][4] = {};
  bf16x8 av[4][2], bv[4][2];

  const int NT = K >> 6;   // 66 K-tiles

  // ---- prologue: stage A(0)->buf0, B(0)->buf0, B(1)->buf1 ----
#pragma unroll
  for (int s = 0; s < 4; ++s) gld16(pA[s], lds + ldsA + (s << 10));
#pragma unroll
  for (int s = 0; s < 4; ++s) gld16(pB[s], lds + ldsB + (s << 10));
#pragma unroll
  for (int s = 0; s < 4; ++s) gld16(pB[s] + 64, lds + 65536 + ldsB + (s << 10));
#pragma unroll
  for (int s = 0; s < 4; ++s) { pA[s] += 64; pB[s] += 128; }

  for (int j = 0; j < NT; ++j) {
    const int buf  = (j & 1) << 16;
    const int obuf = buf ^ 65536;
    // own loads for K-tile j landed (4 youngest = B(j+1) allowed in flight)
    if (j == NT - 1) { asm volatile("s_waitcnt vmcnt(0)" ::: "memory"); }
    else             { asm volatile("s_waitcnt vmcnt(4)" ::: "memory"); }
    BAR;   // all waves' loads for K-tile j landed
    const bool stA = (j + 1 < NT);
    const bool stB = (j + 2 < NT);
    // p0: read A-half0 + B-half0 ; stage A(j+1) slots 0,1 -> other buf
    RDA(buf, 0); RDB(buf, 0);
    if (stA) { gld16(pA[0], lds + obuf + ldsA);
               gld16(pA[1], lds + obuf + ldsA + 1024); }
    BAR; LGKM0; MFMAQ(0, 0); BAR;
    // p1: read B-half1 ; stage A(j+1) slots 2,3
    RDB(buf, 1);
    if (stA) { gld16(pA[2], lds + obuf + ldsA + 2048);
               gld16(pA[3], lds + obuf + ldsA + 3072); }
    BAR; LGKM0; MFMAQ(0, 1); BAR;
    // p2: read A-half1 ; stage B(j+2) slots 0,1 -> this buf (B reads drained at p1)
    RDA(buf, 1);
    if (stB) { gld16(pB[0], lds + buf + ldsB);
               gld16(pB[1], lds + buf + ldsB + 1024); }
    BAR; LGKM0; MFMAQ(1, 1); BAR;
    // p3: no reads ; stage B(j+2) slots 2,3 (A reads drained at p2)
    if (stB) { gld16(pB[2], lds + buf + ldsB + 2048);
               gld16(pB[3], lds + buf + ldsB + 3072); }
    BAR; MFMAQ(1, 0); BAR;
#pragma unroll
    for (int s = 0; s < 4; ++s) { pA[s] += 64; pB[s] += 64; }
  }

  // ---- epilogue: C = acc + bias ----
#pragma unroll
  for (int m = 0; m < 8; ++m) {
    const int row0 = brow + wr * 128 + m * 16 + lhi * 4;
#pragma unroll
    for (int n = 0; n < 4; ++n) {
      const int col = bcol + wc * 64 + n * 16 + l15;
      const float b2 = bias[col];
#pragma unroll
      for (int j = 0; j < 4; ++j)
        C[(size_t)(row0 + j) * ldc + col] = acc[m][n][j] + b2;
    }
  }
}

// ---------- launch ----------
extern "C" void kernel_launch(void* const* d_in, const int* in_sizes, int n_in,
                              void* d_out, int out_size, void* d_ws, size_t ws_size,
                              hipStream_t stream) {
  const float* x  = (const float*)d_in[0];   // [8192][4096]
  const float* Wb = (const float*)d_in[1];   // [4096][4096]
  const float* bb = (const float*)d_in[2];   // [4096]
  const float* Wg = (const float*)d_in[3];   // [8][4096]
  const float* A  = (const float*)d_in[4];   // [8][16][4096] = [128][4096]
  const float* B  = (const float*)d_in[5];   // [8][4096][16]
  float* out = (float*)d_out;                // [8192][4096]

  char* ws = (char*)d_ws;
  u16*   Xaug = (u16*)ws;                                   // 8192 x 4224 bf16
  u16*   Waug = (u16*)(ws + 69206016);                      // 4096 x 4224 bf16
  u16*   a2   = (u16*)(ws + 69206016 + 34603008);           // 128 x 4096 bf16
  float* wsc  = (float*)(ws + 69206016 + 34603008 + 1048576); // 8192 x 8

  // 1) casts into augmented operand buffers
  cast_strided<<<4096, 256, 0, stream>>>(x,  Xaug, 8192, 4096, 4224);
  cast_strided<<<2048, 256, 0, stream>>>(Wb, Waug, 4096, 4096, 4224);
  cast_strided<<<512,  256, 0, stream>>>(A,  a2,   128,  4096, 4096);
  cast_b2<<<2048, 256, 0, stream>>>(B, Waug);

  // 2) gating weights (fp32, exact path)
  gate_kernel<<<2048, 256, 0, stream>>>(x, Wg, wsc);

  // 3) LoRA down-proj + gate-scale -> Xaug[:, 4096:]
  lora_down<<<64, 256, 0, stream>>>(Xaug, a2, wsc, Xaug);

  // 4) main fused GEMM: out = Xaug @ Waug^T + bias (256^2 8-phase, gload_lds)
  gemm8p<<<512, 512, 0, stream>>>(Xaug, Waug, bb, out, 4224, 4224, 4096, 4224, 16);
}

// Round 4
// 393.306 us; speedup vs baseline: 1.6093x; 1.1194x over previous
//
#include <hip/hip_runtime.h>
#include <stdint.h>

typedef unsigned short u16;
typedef float f32x4 __attribute__((ext_vector_type(4)));
typedef short bf16x8 __attribute__((ext_vector_type(8)));

// ---------- helpers ----------
static __device__ __forceinline__ u16 f2bf(float f) {
  union { float f; unsigned u; } a; a.f = f;
  unsigned r = a.u + 0x7fffu + ((a.u >> 16) & 1u);   // round-nearest-even
  return (u16)(r >> 16);
}

static __device__ __forceinline__ void gld16(const void* g, void* l) {
  __builtin_amdgcn_global_load_lds(
      (const __attribute__((address_space(1))) void*)(uintptr_t)g,
      (__attribute__((address_space(3))) void*)(uintptr_t)l,
      16, 0, 0);
}

// ---------- cast fp32 [rows][cols] -> bf16 [rows][ldd] ----------
__global__ __launch_bounds__(256) void cast_strided(
    const float* __restrict__ src, u16* __restrict__ dst,
    int rows, int cols, int ldd) {
  const size_t total = (size_t)rows * cols / 4;
  for (size_t i = (size_t)blockIdx.x * 256 + threadIdx.x; i < total;
       i += (size_t)gridDim.x * 256) {
    const size_t e = i * 4;
    const int r = (int)(e / cols);
    const int c = (int)(e % cols);
    float4 v = *(const float4*)(src + e);
    ushort4 o;
    o.x = f2bf(v.x); o.y = f2bf(v.y); o.z = f2bf(v.z); o.w = f2bf(v.w);
    *(ushort4*)(dst + (size_t)r * ldd + c) = o;
  }
}

// ---------- B [E=8][O=4096][R=16] * SCALING -> Waug[:, 4096:4224] bf16 ----------
__global__ __launch_bounds__(256) void cast_b2(
    const float* __restrict__ B, u16* __restrict__ Waug) {
  int i = blockIdx.x * 256 + threadIdx.x;
  if (i >= 4096 * 128) return;
  const int o = i >> 7;
  const int er = i & 127;
  const int e = er >> 4;
  const int r = er & 15;
  float v = B[((size_t)e * 4096 + o) * 16 + r] * 2.0f;   // SCALING = 32/16
  Waug[(size_t)o * 4224 + 4096 + er] = f2bf(v);
}

// ---------- fused: cast x -> Xaug base cols AND compute gate weights ----------
// 1 wave per token: cast 4096 floats to bf16, accumulate 8 expert dots (fp32 exact),
// shfl-reduce, softmax-top2-renorm -> wsc[n][e]
__global__ __launch_bounds__(256) void cast_x_gate(
    const float* __restrict__ x, const float* __restrict__ Wg,
    u16* __restrict__ Xaug, float* __restrict__ wsc) {
  const int lane = threadIdx.x & 63;
  const int wv = threadIdx.x >> 6;
  const int n = blockIdx.x * 4 + wv;
  const float4* x4 = (const float4*)(x + (size_t)n * 4096);
  const float4* g4 = (const float4*)Wg;                  // [8][1024] float4
  u16* xr = Xaug + (size_t)n * 4224;
  float acc[8] = {0, 0, 0, 0, 0, 0, 0, 0};
#pragma unroll
  for (int ii = 0; ii < 16; ++ii) {
    const int i = ii * 64 + lane;
    float4 xv = x4[i];
    ushort4 o;
    o.x = f2bf(xv.x); o.y = f2bf(xv.y); o.z = f2bf(xv.z); o.w = f2bf(xv.w);
    *(ushort4*)(xr + i * 4) = o;
#pragma unroll
    for (int e = 0; e < 8; ++e) {
      float4 w4 = g4[e * 1024 + i];
      acc[e] += xv.x * w4.x + xv.y * w4.y + xv.z * w4.z + xv.w * w4.w;
    }
  }
#pragma unroll
  for (int e = 0; e < 8; ++e) {
#pragma unroll
    for (int off = 32; off > 0; off >>= 1)
      acc[e] += __shfl_xor(acc[e], off);
  }
  int i1 = 0; float m1 = acc[0];
#pragma unroll
  for (int e = 1; e < 8; ++e) if (acc[e] > m1) { m1 = acc[e]; i1 = e; }
  int i2 = -1; float m2 = -3.4e38f;
#pragma unroll
  for (int e = 0; e < 8; ++e) if (e != i1 && acc[e] > m2) { m2 = acc[e]; i2 = e; }
  float w1 = 1.0f / (1.0f + expf(m2 - m1));   // p1/(p1+p2) after softmax+renorm
  float w2 = 1.0f - w1;
  if (lane < 8)
    wsc[(size_t)n * 8 + lane] = (lane == i1) ? w1 : ((lane == i2) ? w2 : 0.0f);
}

// ---------- LoRA down-proj, split-K x4 -> f32 partials in hp ----------
// hp[ky][n][er] = sum_{k in ky-chunk} Xaug[n][k] * a2[er][k]
__global__ __launch_bounds__(256) void lora_down(
    const u16* __restrict__ Xa, const u16* __restrict__ A2,
    float* __restrict__ hp) {
  __shared__ u16 sA[128 * 64];
  __shared__ u16 sB[128 * 64];
  const int t = threadIdx.x;
  const int lane = t & 63;
  const int wr = t >> 7;
  const int wc = (t >> 6) & 1;
  const int l15 = lane & 15;
  const int lhi = lane >> 4;
  f32x4 acc[4][4] = {};

  const int brow = blockIdx.x * 128;
  const int kbase = blockIdx.y * 1024;
  const int srow = t >> 3;
  const int scol = (t & 7) * 8;
  const size_t a_src = (size_t)(brow + srow) * 4224 + scol + kbase;
  const size_t b_src = (size_t)srow * 4096 + scol + kbase;

  for (int k0 = 0; k0 < 1024; k0 += 64) {
#pragma unroll
    for (int c = 0; c < 4; ++c)
      gld16(Xa + a_src + (size_t)c * 32 * 4224 + k0,
            &sA[(c * 32 + srow) * 64 + scol]);
#pragma unroll
    for (int c = 0; c < 4; ++c)
      gld16(A2 + b_src + (size_t)c * 32 * 4096 + k0,
            &sB[(c * 32 + srow) * 64 + scol]);
    __syncthreads();
#pragma unroll
    for (int kk = 0; kk < 2; ++kk) {
      bf16x8 av[4], bv[4];
#pragma unroll
      for (int m = 0; m < 4; ++m)
        av[m] = *(const bf16x8*)&sA[(wr * 64 + m * 16 + l15) * 64 + kk * 32 + lhi * 8];
#pragma unroll
      for (int n = 0; n < 4; ++n)
        bv[n] = *(const bf16x8*)&sB[(wc * 64 + n * 16 + l15) * 64 + kk * 32 + lhi * 8];
#pragma unroll
      for (int m = 0; m < 4; ++m)
#pragma unroll
        for (int n = 0; n < 4; ++n)
          acc[m][n] = __builtin_amdgcn_mfma_f32_16x16x32_bf16(av[m], bv[n], acc[m][n], 0, 0, 0);
    }
    __syncthreads();
  }
  float* out = hp + (size_t)blockIdx.y * (8192 * 128);
#pragma unroll
  for (int m = 0; m < 4; ++m) {
    const int rbase = brow + wr * 64 + m * 16 + lhi * 4;
#pragma unroll
    for (int n = 0; n < 4; ++n) {
      const int col = wc * 64 + n * 16 + l15;   // 0..127
#pragma unroll
      for (int j = 0; j < 4; ++j)
        out[(size_t)(rbase + j) * 128 + col] = acc[m][n][j];
    }
  }
}

// ---------- reduce split-K partials, apply gate weight, store bf16 to Xaug ----------
__global__ __launch_bounds__(256) void reduce_hw(
    const float* __restrict__ hp, const float* __restrict__ wsc,
    u16* __restrict__ Xaug) {
  int i = blockIdx.x * 256 + threadIdx.x;
  if (i >= 8192 * 128) return;
  const int n = i >> 7;
  const int er = i & 127;
  const int e = er >> 4;
  float v = hp[i] + hp[i + 1048576] + hp[i + 2097152] + hp[i + 3145728];
  Xaug[(size_t)n * 4224 + 4096 + er] = f2bf(v * wsc[n * 8 + e]);
}

// ================== 256x256 8-phase main GEMM (global_load_lds, pre-swizzled src) ==================
// BM=BN=256, BK=64, 512 thr (8 waves 2x4), per-wave 128x64 out.
// LDS: 2 bufs x (A 32KB + B 32KB), st_16x32 XOR swizzle via pre-swizzled global src.
// ONE barrier per phase (phase-end). Every ds_read of a phase is consumed by that
// phase's MFMAs -> compiler's auto lgkmcnt drains reads before the wave reaches the
// phase-end barrier, so all staging-write-vs-read pairs are gated by phase-end
// barriers alone.  Counted vmcnt(4) folded into p3-end (vmcnt(0) only at tail).
#define BAR do { asm volatile("" ::: "memory"); __builtin_amdgcn_s_barrier(); asm volatile("" ::: "memory"); } while (0)

#define RDA(BUF, MH)                                                            \
  { _Pragma("unroll") for (int mm = 0; mm < 4; ++mm)                            \
    _Pragma("unroll") for (int kk = 0; kk < 2; ++kk)                            \
      av[mm][kk] = *(const bf16x8*)(lds + (BUF) + fbA + ((((MH) * 4 + mm) * 2 + kk) << 10)); }

#define RDB(BUF, NH)                                                            \
  { _Pragma("unroll") for (int nn = 0; nn < 2; ++nn)                            \
    _Pragma("unroll") for (int kk = 0; kk < 2; ++kk)                            \
      bv[(NH) * 2 + nn][kk] = *(const bf16x8*)(lds + (BUF) + fbB + ((((NH) * 2 + nn) * 2 + kk) << 10)); }

#define MFMAQ(MH, NH)                                                           \
  { __builtin_amdgcn_s_setprio(1);                                              \
    _Pragma("unroll") for (int kk = 0; kk < 2; ++kk)                            \
    _Pragma("unroll") for (int mm = 0; mm < 4; ++mm)                            \
    _Pragma("unroll") for (int nn = 0; nn < 2; ++nn)                            \
      acc[(MH) * 4 + mm][(NH) * 2 + nn] = __builtin_amdgcn_mfma_f32_16x16x32_bf16( \
          av[mm][kk], bv[(NH) * 2 + nn][kk], acc[(MH) * 4 + mm][(NH) * 2 + nn], 0, 0, 0); \
    __builtin_amdgcn_s_setprio(0); }

__global__ __launch_bounds__(512, 2) void gemm8p(
    const u16* __restrict__ Ag, const u16* __restrict__ Bg,
    const float* __restrict__ bias, float* __restrict__ C,
    int lda, int ldb, int ldc, int K, int tiles_n) {
  __shared__ __align__(1024) char lds[131072];
  const int t = threadIdx.x;
  const int lane = t & 63;
  const int w = t >> 6;
  const int wr = w >> 2, wc = w & 3;
  const int l15 = lane & 15, lhi = lane >> 4;

  // bijective XCD swizzle (gridDim.x % 8 == 0)
  const int cpx = gridDim.x >> 3;
  const int bid = blockIdx.x;
  const int swz = (bid & 7) * cpx + (bid >> 3);
  const int tile_m = swz / tiles_n;
  const int tile_n = swz % tiles_n;
  const int brow = tile_m << 8;
  const int bcol = tile_n << 8;

  // pre-swizzled per-lane source coords (st_16x32 involution)
  const int sb = (lane << 4) ^ (lane & 32);
  const int srow = sb >> 6;
  const int scol = (sb & 63) >> 1;

  // wave w stages A subtiles w*4..w*4+3 and B subtiles w*4..w*4+3 per K-tile
  const u16* pA[4]; const u16* pB[4];
#pragma unroll
  for (int s = 0; s < 4; ++s) {
    const int idx = w * 4 + s;
    const int rg = idx >> 1, cs = idx & 1;
    pA[s] = Ag + (size_t)(brow + rg * 16 + srow) * lda + cs * 32 + scol;
    pB[s] = Bg + (size_t)(bcol + rg * 16 + srow) * ldb + cs * 32 + scol;
  }
  const int ldsA = w << 12;
  const int ldsB = 32768 + (w << 12);

  // fragment read bases (swizzled read of linear-written LDS)
  const int innerL = ((l15 << 6) + (lhi << 4)) ^ ((l15 & 8) << 2);
  const int fbA = (wr << 14) + innerL;
  const int fbB = 32768 + (wc << 13) + innerL;

  f32x4 acc[8][4] = {};
  bf16x8 av[4][2], bv[4][2];

  const int NT = K >> 6;   // 66 K-tiles

  // ---- prologue: stage A(0)->buf0, B(0)->buf0, B(1)->buf1 ----
#pragma unroll
  for (int s = 0; s < 4; ++s) gld16(pA[s], lds + ldsA + (s << 10));
#pragma unroll
  for (int s = 0; s < 4; ++s) gld16(pB[s], lds + ldsB + (s << 10));
#pragma unroll
  for (int s = 0; s < 4; ++s) gld16(pB[s] + 64, lds + 65536 + ldsB + (s << 10));
#pragma unroll
  for (int s = 0; s < 4; ++s) { pA[s] += 64; pB[s] += 128; }
  asm volatile("s_waitcnt vmcnt(4)" ::: "memory");   // A(0),B(0) landed
  BAR;

  for (int j = 0; j < NT; ++j) {
    const int buf  = (j & 1) << 16;
    const int obuf = buf ^ 65536;
    const bool stA = (j + 1 < NT);
    const bool stB = (j + 2 < NT);
    // p0: read A-half0 + B-half0 ; stage A(j+1) slots 0,1 -> other buf
    RDA(buf, 0); RDB(buf, 0);
    if (stA) { gld16(pA[0], lds + obuf + ldsA);
               gld16(pA[1], lds + obuf + ldsA + 1024); }
    MFMAQ(0, 0); BAR;
    // p1: read B-half1 ; stage A(j+1) slots 2,3
    RDB(buf, 1);
    if (stA) { gld16(pA[2], lds + obuf + ldsA + 2048);
               gld16(pA[3], lds + obuf + ldsA + 3072); }
    MFMAQ(0, 1); BAR;
    // p2: read A-half1 ; stage B(j+2) slots 0,1 -> this buf (B reads drained @ p1-end)
    RDA(buf, 1);
    if (stB) { gld16(pB[0], lds + buf + ldsB);
               gld16(pB[1], lds + buf + ldsB + 1024); }
    MFMAQ(1, 1); BAR;
    // p3: stage B(j+2) slots 2,3 (A reads drained @ p2-end); vmcnt for next tile
    if (stB) { gld16(pB[2], lds + buf + ldsB + 2048);
               gld16(pB[3], lds + buf + ldsB + 3072); }
    MFMAQ(1, 0);
    if (j < NT - 2)       { asm volatile("s_waitcnt vmcnt(4)" ::: "memory"); }
    else if (j == NT - 2) { asm volatile("s_waitcnt vmcnt(0)" ::: "memory"); }
    BAR;
#pragma unroll
    for (int s = 0; s < 4; ++s) { pA[s] += 64; pB[s] += 64; }
  }

  // ---- epilogue: C = acc + bias ----
#pragma unroll
  for (int m = 0; m < 8; ++m) {
    const int row0 = brow + wr * 128 + m * 16 + lhi * 4;
#pragma unroll
    for (int n = 0; n < 4; ++n) {
      const int col = bcol + wc * 64 + n * 16 + l15;
      const float b2 = bias[col];
#pragma unroll
      for (int j = 0; j < 4; ++j)
        C[(size_t)(row0 + j) * ldc + col] = acc[m][n][j] + b2;
    }
  }
}

// ---------- launch ----------
extern "C" void kernel_launch(void* const* d_in, const int* in_sizes, int n_in,
                              void* d_out, int out_size, void* d_ws, size_t ws_size,
                              hipStream_t stream) {
  const float* x  = (const float*)d_in[0];   // [8192][4096]
  const float* Wb = (const float*)d_in[1];   // [4096][4096]
  const float* bb = (const float*)d_in[2];   // [4096]
  const float* Wg = (const float*)d_in[3];   // [8][4096]
  const float* A  = (const float*)d_in[4];   // [8][16][4096] = [128][4096]
  const float* B  = (const float*)d_in[5];   // [8][4096][16]
  float* out = (float*)d_out;                // [8192][4096]

  char* ws = (char*)d_ws;
  u16*   Xaug = (u16*)ws;                                     // 8192 x 4224 bf16
  u16*   Waug = (u16*)(ws + 69206016);                        // 4096 x 4224 bf16
  u16*   a2   = (u16*)(ws + 69206016 + 34603008);             // 128 x 4096 bf16
  float* wsc  = (float*)(ws + 69206016 + 34603008 + 1048576); // 8192 x 8
  // split-K partials live in d_out (16 MB; fully overwritten by gemm8p afterwards)
  float* hp   = out;

  // 1) cast x -> Xaug base + gate weights (fused; x read once)
  cast_x_gate<<<2048, 256, 0, stream>>>(x, Wg, Xaug, wsc);

  // 2) other casts
  cast_strided<<<2048, 256, 0, stream>>>(Wb, Waug, 4096, 4096, 4224);
  cast_strided<<<512,  256, 0, stream>>>(A,  a2,   128,  4096, 4096);
  cast_b2<<<2048, 256, 0, stream>>>(B, Waug);

  // 3) LoRA down-proj, split-K x4 -> partials in d_out
  lora_down<<<dim3(64, 4), 256, 0, stream>>>(Xaug, a2, hp);

  // 4) reduce partials + gate-scale -> Xaug[:, 4096:]
  reduce_hw<<<4096, 256, 0, stream>>>(hp, wsc, Xaug);

  // 5) main fused GEMM: out = Xaug @ Waug^T + bias (256^2 8-phase, gload_lds)
  gemm8p<<<512, 512, 0, stream>>>(Xaug, Waug, bb, out, 4224, 4224, 4096, 4224, 16);
}

// Round 5
// 391.881 us; speedup vs baseline: 1.6152x; 1.0036x over previous
//
#include <hip/hip_runtime.h>
#include <stdint.h>

typedef unsigned short u16;
typedef float f32x4 __attribute__((ext_vector_type(4)));
typedef short bf16x8 __attribute__((ext_vector_type(8)));

// ---------- helpers ----------
static __device__ __forceinline__ u16 f2bf(float f) {
  union { float f; unsigned u; } a; a.f = f;
  unsigned r = a.u + 0x7fffu + ((a.u >> 16) & 1u);   // round-nearest-even
  return (u16)(r >> 16);
}

static __device__ __forceinline__ void gld16(const void* g, void* l) {
  __builtin_amdgcn_global_load_lds(
      (const __attribute__((address_space(1))) void*)(uintptr_t)g,
      (__attribute__((address_space(3))) void*)(uintptr_t)l,
      16, 0, 0);
}

// ---------- cast fp32 [rows][cols] -> bf16 [rows][ldd] ----------
__global__ __launch_bounds__(256) void cast_strided(
    const float* __restrict__ src, u16* __restrict__ dst,
    int rows, int cols, int ldd) {
  const size_t total = (size_t)rows * cols / 4;
  for (size_t i = (size_t)blockIdx.x * 256 + threadIdx.x; i < total;
       i += (size_t)gridDim.x * 256) {
    const size_t e = i * 4;
    const int r = (int)(e / cols);
    const int c = (int)(e % cols);
    float4 v = *(const float4*)(src + e);
    ushort4 o;
    o.x = f2bf(v.x); o.y = f2bf(v.y); o.z = f2bf(v.z); o.w = f2bf(v.w);
    *(ushort4*)(dst + (size_t)r * ldd + c) = o;
  }
}

// ---------- B [E=8][O=4096][R=16] * SCALING -> Waug[:, 4096:4224] bf16 ----------
__global__ __launch_bounds__(256) void cast_b2(
    const float* __restrict__ B, u16* __restrict__ Waug) {
  int i = blockIdx.x * 256 + threadIdx.x;
  if (i >= 4096 * 128) return;
  const int o = i >> 7;
  const int er = i & 127;
  const int e = er >> 4;
  const int r = er & 15;
  float v = B[((size_t)e * 4096 + o) * 16 + r] * 2.0f;   // SCALING = 32/16
  Waug[(size_t)o * 4224 + 4096 + er] = f2bf(v);
}

// ---------- fused: cast x -> Xaug base cols AND compute gate weights ----------
__global__ __launch_bounds__(256) void cast_x_gate(
    const float* __restrict__ x, const float* __restrict__ Wg,
    u16* __restrict__ Xaug, float* __restrict__ wsc) {
  const int lane = threadIdx.x & 63;
  const int wv = threadIdx.x >> 6;
  const int n = blockIdx.x * 4 + wv;
  const float4* x4 = (const float4*)(x + (size_t)n * 4096);
  const float4* g4 = (const float4*)Wg;                  // [8][1024] float4
  u16* xr = Xaug + (size_t)n * 4224;
  float acc[8] = {0, 0, 0, 0, 0, 0, 0, 0};
#pragma unroll
  for (int ii = 0; ii < 16; ++ii) {
    const int i = ii * 64 + lane;
    float4 xv = x4[i];
    ushort4 o;
    o.x = f2bf(xv.x); o.y = f2bf(xv.y); o.z = f2bf(xv.z); o.w = f2bf(xv.w);
    *(ushort4*)(xr + i * 4) = o;
#pragma unroll
    for (int e = 0; e < 8; ++e) {
      float4 w4 = g4[e * 1024 + i];
      acc[e] += xv.x * w4.x + xv.y * w4.y + xv.z * w4.z + xv.w * w4.w;
    }
  }
#pragma unroll
  for (int e = 0; e < 8; ++e) {
#pragma unroll
    for (int off = 32; off > 0; off >>= 1)
      acc[e] += __shfl_xor(acc[e], off);
  }
  int i1 = 0; float m1 = acc[0];
#pragma unroll
  for (int e = 1; e < 8; ++e) if (acc[e] > m1) { m1 = acc[e]; i1 = e; }
  int i2 = -1; float m2 = -3.4e38f;
#pragma unroll
  for (int e = 0; e < 8; ++e) if (e != i1 && acc[e] > m2) { m2 = acc[e]; i2 = e; }
  float w1 = 1.0f / (1.0f + expf(m2 - m1));   // p1/(p1+p2) after softmax+renorm
  float w2 = 1.0f - w1;
  if (lane < 8)
    wsc[(size_t)n * 8 + lane] = (lane == i1) ? w1 : ((lane == i2) ? w2 : 0.0f);
}

// ---------- LoRA down-proj, split-K x4 -> f32 partials in hp ----------
__global__ __launch_bounds__(256) void lora_down(
    const u16* __restrict__ Xa, const u16* __restrict__ A2,
    float* __restrict__ hp) {
  __shared__ u16 sA[128 * 64];
  __shared__ u16 sB[128 * 64];
  const int t = threadIdx.x;
  const int lane = t & 63;
  const int wr = t >> 7;
  const int wc = (t >> 6) & 1;
  const int l15 = lane & 15;
  const int lhi = lane >> 4;
  f32x4 acc[4][4] = {};

  const int brow = blockIdx.x * 128;
  const int kbase = blockIdx.y * 1024;
  const int srow = t >> 3;
  const int scol = (t & 7) * 8;
  const size_t a_src = (size_t)(brow + srow) * 4224 + scol + kbase;
  const size_t b_src = (size_t)srow * 4096 + scol + kbase;

  for (int k0 = 0; k0 < 1024; k0 += 64) {
#pragma unroll
    for (int c = 0; c < 4; ++c)
      gld16(Xa + a_src + (size_t)c * 32 * 4224 + k0,
            &sA[(c * 32 + srow) * 64 + scol]);
#pragma unroll
    for (int c = 0; c < 4; ++c)
      gld16(A2 + b_src + (size_t)c * 32 * 4096 + k0,
            &sB[(c * 32 + srow) * 64 + scol]);
    __syncthreads();
#pragma unroll
    for (int kk = 0; kk < 2; ++kk) {
      bf16x8 av[4], bv[4];
#pragma unroll
      for (int m = 0; m < 4; ++m)
        av[m] = *(const bf16x8*)&sA[(wr * 64 + m * 16 + l15) * 64 + kk * 32 + lhi * 8];
#pragma unroll
      for (int n = 0; n < 4; ++n)
        bv[n] = *(const bf16x8*)&sB[(wc * 64 + n * 16 + l15) * 64 + kk * 32 + lhi * 8];
#pragma unroll
      for (int m = 0; m < 4; ++m)
#pragma unroll
        for (int n = 0; n < 4; ++n)
          acc[m][n] = __builtin_amdgcn_mfma_f32_16x16x32_bf16(av[m], bv[n], acc[m][n], 0, 0, 0);
    }
    __syncthreads();
  }
  float* out = hp + (size_t)blockIdx.y * (8192 * 128);
#pragma unroll
  for (int m = 0; m < 4; ++m) {
    const int rbase = brow + wr * 64 + m * 16 + lhi * 4;
#pragma unroll
    for (int n = 0; n < 4; ++n) {
      const int col = wc * 64 + n * 16 + l15;   // 0..127
#pragma unroll
      for (int j = 0; j < 4; ++j)
        out[(size_t)(rbase + j) * 128 + col] = acc[m][n][j];
    }
  }
}

// ---------- reduce split-K partials, apply gate weight, store bf16 to Xaug ----------
__global__ __launch_bounds__(256) void reduce_hw(
    const float* __restrict__ hp, const float* __restrict__ wsc,
    u16* __restrict__ Xaug) {
  int i = blockIdx.x * 256 + threadIdx.x;
  if (i >= 8192 * 128) return;
  const int n = i >> 7;
  const int er = i & 127;
  const int e = er >> 4;
  float v = hp[i] + hp[i + 1048576] + hp[i + 2097152] + hp[i + 3145728];
  Xaug[(size_t)n * 4224 + 4096 + er] = f2bf(v * wsc[n * 8 + e]);
}

// ================== 256x256 8-phase main GEMM (pipelined ds_reads) ==================
// BM=BN=256, BK=64, 512 thr (8 waves 2x4), per-wave 128x64 out.
// LDS: 2 bufs x (A 32KB + B 32KB), st_16x32 XOR swizzle via pre-swizzled global src.
// SOFTWARE-PIPELINED READS: each phase's ds_reads are issued AFTER the previous
// phase's MFMA cluster (their destination regs die at that cluster's issue), so
// read latency spans the phase-end barrier and hides under the other wave's MFMAs.
// Quadrant order (0,0)->(0,1)->(1,1)->(1,0) makes this register-neutral:
//   p3(j-1): read av0(j),bv01(j)   p0: M[av0,bv01], read bv23
//   p1: M[av0,bv23], read av1      p2: M[av1,bv23]
//   p3: vmcnt(4)+BAR, M[av1,bv01], read av0',bv01' from next buf
// Staging (gld16): A(j+1) at p0/p1 -> other buf, B(j+2) at p2/p3 -> this buf.
// All WAR pairs gated by phase-end barriers; next-buf reads gated by vmcnt(4)+BAR.
#define BAR do { asm volatile("" ::: "memory"); __builtin_amdgcn_s_barrier(); asm volatile("" ::: "memory"); } while (0)

#define RDA(BUF, MH)                                                            \
  { _Pragma("unroll") for (int mm = 0; mm < 4; ++mm)                            \
    _Pragma("unroll") for (int kk = 0; kk < 2; ++kk)                            \
      av[mm][kk] = *(const bf16x8*)(lds + (BUF) + fbA + ((((MH) * 4 + mm) * 2 + kk) << 10)); }

#define RDB(BUF, NH)                                                            \
  { _Pragma("unroll") for (int nn = 0; nn < 2; ++nn)                            \
    _Pragma("unroll") for (int kk = 0; kk < 2; ++kk)                            \
      bv[(NH) * 2 + nn][kk] = *(const bf16x8*)(lds + (BUF) + fbB + ((((NH) * 2 + nn) * 2 + kk) << 10)); }

#define MFMAQ(MH, NH)                                                           \
  { __builtin_amdgcn_s_setprio(1);                                              \
    _Pragma("unroll") for (int kk = 0; kk < 2; ++kk)                            \
    _Pragma("unroll") for (int mm = 0; mm < 4; ++mm)                            \
    _Pragma("unroll") for (int nn = 0; nn < 2; ++nn)                            \
      acc[(MH) * 4 + mm][(NH) * 2 + nn] = __builtin_amdgcn_mfma_f32_16x16x32_bf16( \
          av[mm][kk], bv[(NH) * 2 + nn][kk], acc[(MH) * 4 + mm][(NH) * 2 + nn], 0, 0, 0); \
    __builtin_amdgcn_s_setprio(0); }

__global__ __launch_bounds__(512, 2) void gemm8p(
    const u16* __restrict__ Ag, const u16* __restrict__ Bg,
    const float* __restrict__ bias, float* __restrict__ C,
    int lda, int ldb, int ldc, int K, int tiles_n) {
  __shared__ __align__(1024) char lds[131072];
  const int t = threadIdx.x;
  const int lane = t & 63;
  const int w = t >> 6;
  const int wr = w >> 2, wc = w & 3;
  const int l15 = lane & 15, lhi = lane >> 4;

  // bijective XCD swizzle (gridDim.x % 8 == 0)
  const int cpx = gridDim.x >> 3;
  const int bid = blockIdx.x;
  const int swz = (bid & 7) * cpx + (bid >> 3);
  const int tile_m = swz / tiles_n;
  const int tile_n = swz % tiles_n;
  const int brow = tile_m << 8;
  const int bcol = tile_n << 8;

  // pre-swizzled per-lane source coords (st_16x32 involution)
  const int sb = (lane << 4) ^ (lane & 32);
  const int srow = sb >> 6;
  const int scol = (sb & 63) >> 1;

  // wave w stages A subtiles w*4..w*4+3 and B subtiles w*4..w*4+3 per K-tile
  const u16* pA[4]; const u16* pB[4];
#pragma unroll
  for (int s = 0; s < 4; ++s) {
    const int idx = w * 4 + s;
    const int rg = idx >> 1, cs = idx & 1;
    pA[s] = Ag + (size_t)(brow + rg * 16 + srow) * lda + cs * 32 + scol;
    pB[s] = Bg + (size_t)(bcol + rg * 16 + srow) * ldb + cs * 32 + scol;
  }
  const int ldsA = w << 12;
  const int ldsB = 32768 + (w << 12);

  // fragment read bases (swizzled read of linear-written LDS)
  const int innerL = ((l15 << 6) + (lhi << 4)) ^ ((l15 & 8) << 2);
  const int fbA = (wr << 14) + innerL;
  const int fbB = 32768 + (wc << 13) + innerL;

  f32x4 acc[8][4] = {};
  bf16x8 av[4][2], bv[4][2];

  const int NT = K >> 6;   // 66 K-tiles

  // ---- prologue: stage A(0)->buf0, B(0)->buf0, B(1)->buf1 ----
#pragma unroll
  for (int s = 0; s < 4; ++s) gld16(pA[s], lds + ldsA + (s << 10));
#pragma unroll
  for (int s = 0; s < 4; ++s) gld16(pB[s], lds + ldsB + (s << 10));
#pragma unroll
  for (int s = 0; s < 4; ++s) gld16(pB[s] + 64, lds + 65536 + ldsB + (s << 10));
#pragma unroll
  for (int s = 0; s < 4; ++s) { pA[s] += 64; pB[s] += 128; }
  asm volatile("s_waitcnt vmcnt(4)" ::: "memory");   // A(0),B(0) landed
  BAR;
  RDA(0, 0); RDB(0, 0);    // av0(0), bv01(0) for first M0

  for (int j = 0; j < NT; ++j) {
    const int buf  = (j & 1) << 16;
    const int obuf = buf ^ 65536;
    const bool stA = (j + 1 < NT);
    const bool stB = (j + 2 < NT);
    // p0: stage A(j+1)[0,1]; M0 [av0,bv01]; read bv23 (regs free)
    if (stA) { gld16(pA[0], lds + obuf + ldsA);
               gld16(pA[1], lds + obuf + ldsA + 1024); }
    MFMAQ(0, 0);
    RDB(buf, 1);
    BAR;
    // p1: stage A(j+1)[2,3]; M1 [av0,bv23]; read av1 (av regs die at M1 issue)
    if (stA) { gld16(pA[2], lds + obuf + ldsA + 2048);
               gld16(pA[3], lds + obuf + ldsA + 3072); }
    MFMAQ(0, 1);
    RDA(buf, 1);
    BAR;
    // p2: stage B(j+2)[0,1] -> this buf (bv01(j) consumed at M0, bv23 at M1); M2 [av1,bv23]
    if (stB) { gld16(pB[0], lds + buf + ldsB);
               gld16(pB[1], lds + buf + ldsB + 1024); }
    MFMAQ(1, 1);
    BAR;
    // p3: stage B(j+2)[2,3]; vmcnt(4)+BAR (A(j+1),B(j+1) landed);
    //     M3 [av1,bv01]; read av0',bv01' from next buf (regs die at M3 issue)
    if (stB) { gld16(pB[2], lds + buf + ldsB + 2048);
               gld16(pB[3], lds + buf + ldsB + 3072); }
    if (j < NT - 2)       { asm volatile("s_waitcnt vmcnt(4)" ::: "memory"); }
    else if (j == NT - 2) { asm volatile("s_waitcnt vmcnt(0)" ::: "memory"); }
    BAR;
    MFMAQ(1, 0);
    if (stA) { RDA(obuf, 0); RDB(obuf, 0); }
#pragma unroll
    for (int s = 0; s < 4; ++s) { pA[s] += 64; pB[s] += 64; }
  }

  // ---- epilogue: C = acc + bias ----
#pragma unroll
  for (int m = 0; m < 8; ++m) {
    const int row0 = brow + wr * 128 + m * 16 + lhi * 4;
#pragma unroll
    for (int n = 0; n < 4; ++n) {
      const int col = bcol + wc * 64 + n * 16 + l15;
      const float b2 = bias[col];
#pragma unroll
      for (int j = 0; j < 4; ++j)
        C[(size_t)(row0 + j) * ldc + col] = acc[m][n][j] + b2;
    }
  }
}

// ---------- launch ----------
extern "C" void kernel_launch(void* const* d_in, const int* in_sizes, int n_in,
                              void* d_out, int out_size, void* d_ws, size_t ws_size,
                              hipStream_t stream) {
  const float* x  = (const float*)d_in[0];   // [8192][4096]
  const float* Wb = (const float*)d_in[1];   // [4096][4096]
  const float* bb = (const float*)d_in[2];   // [4096]
  const float* Wg = (const float*)d_in[3];   // [8][4096]
  const float* A  = (const float*)d_in[4];   // [8][16][4096] = [128][4096]
  const float* B  = (const float*)d_in[5];   // [8][4096][16]
  float* out = (float*)d_out;                // [8192][4096]

  char* ws = (char*)d_ws;
  u16*   Xaug = (u16*)ws;                                     // 8192 x 4224 bf16
  u16*   Waug = (u16*)(ws + 69206016);                        // 4096 x 4224 bf16
  u16*   a2   = (u16*)(ws + 69206016 + 34603008);             // 128 x 4096 bf16
  float* wsc  = (float*)(ws + 69206016 + 34603008 + 1048576); // 8192 x 8
  // split-K partials live in d_out (16 MB; fully overwritten by gemm8p afterwards)
  float* hp   = out;

  // 1) cast x -> Xaug base + gate weights (fused; x read once)
  cast_x_gate<<<2048, 256, 0, stream>>>(x, Wg, Xaug, wsc);

  // 2) other casts
  cast_strided<<<2048, 256, 0, stream>>>(Wb, Waug, 4096, 4096, 4224);
  cast_strided<<<512,  256, 0, stream>>>(A,  a2,   128,  4096, 4096);
  cast_b2<<<2048, 256, 0, stream>>>(B, Waug);

  // 3) LoRA down-proj, split-K x4 -> partials in d_out
  lora_down<<<dim3(64, 4), 256, 0, stream>>>(Xaug, a2, hp);

  // 4) reduce partials + gate-scale -> Xaug[:, 4096:]
  reduce_hw<<<4096, 256, 0, stream>>>(hp, wsc, Xaug);

  // 5) main fused GEMM: out = Xaug @ Waug^T + bias (256^2, pipelined reads)
  gemm8p<<<512, 512, 0, stream>>>(Xaug, Waug, bb, out, 4224, 4224, 4096, 4224, 16);
}